// Round 3
// baseline (472.502 us; speedup 1.0000x reference)
//
#include <hip/hip_runtime.h>
#include <math.h>

#define EPS_BN 1e-5f
#define SCAN_EPB 1024

// ---------------------------------------------------------------------------
// k_pre: zero icnt/gsum/gcnt + fold conv-bias + BN(eval) into scale/shift
// ---------------------------------------------------------------------------
__global__ __launch_bounds__(256) void k_pre(int* icnt, float* gsum, float* gcnt, int n,
    const float* b1, const float* g1, const float* bb1, const float* m1, const float* v1,
    const float* b2, const float* g2, const float* bb2, const float* m2, const float* v2,
    float* sc1, float* sh1, float* sc2, float* sh2) {
    int i = blockIdx.x * 256 + threadIdx.x;
    if (i < n) icnt[i] = 0;
    if (i < 4096) gsum[i] = 0.0f;
    if (i < 64) gcnt[i] = 0.0f;
    if (blockIdx.x == 0 && threadIdx.x < 64) {
        int t = threadIdx.x;
        float s1 = g1[t] / sqrtf(v1[t] + EPS_BN);
        sc1[t] = s1;
        sh1[t] = (b1[t] - m1[t]) * s1 + bb1[t];
        float s2 = g2[t] / sqrtf(v2[t] + EPS_BN);
        sc2[t] = s2;
        sh2[t] = (b2[t] - m2[t]) * s2 + bb2[t];
    }
}

// ---------------------------------------------------------------------------
// k_histgemm: block role split. Blocks [0,nbg): GEMM1 out = x @ W1^T.
// Blocks [nbg,...): in-degree histogram, 4 edges/thread (int4).
// The two halves have no data dependency on each other.
// ---------------------------------------------------------------------------
__global__ __launch_bounds__(256) void k_histgemm(int nbg,
    const float* __restrict__ in, const float* __restrict__ W, float* __restrict__ out, int n,
    const int* __restrict__ col, int* icnt, int e) {
    __shared__ float4 Wl[1024];  // [h][f4]
    if ((int)blockIdx.x < nbg) {
        const float4* W4 = (const float4*)W;
        for (int i = threadIdx.x; i < 1024; i += 256) Wl[i] = W4[i];
        __syncthreads();
        int hg = threadIdx.x >> 6;  // wave-uniform
        int h0 = hg * 16;
        int ng = threadIdx.x & 63;
        int n0 = blockIdx.x * 256 + 4 * ng;
        float acc[4][16];
#pragma unroll
        for (int j = 0; j < 4; ++j)
#pragma unroll
            for (int k = 0; k < 16; ++k) acc[j][k] = 0.0f;
        const float4* in4 = (const float4*)in;
        bool valid[4];
#pragma unroll
        for (int j = 0; j < 4; ++j) valid[j] = (n0 + j) < n;
        for (int f4 = 0; f4 < 16; ++f4) {
            float4 xv[4];
#pragma unroll
            for (int j = 0; j < 4; ++j)
                xv[j] = valid[j] ? in4[(n0 + j) * 16 + f4] : float4{0.f, 0.f, 0.f, 0.f};
#pragma unroll
            for (int hh = 0; hh < 16; ++hh) {
                float4 w = Wl[(h0 + hh) * 16 + f4];
#pragma unroll
                for (int j = 0; j < 4; ++j) {
                    acc[j][hh] += xv[j].x * w.x;
                    acc[j][hh] += xv[j].y * w.y;
                    acc[j][hh] += xv[j].z * w.z;
                    acc[j][hh] += xv[j].w * w.w;
                }
            }
        }
        float4* out4 = (float4*)out;
#pragma unroll
        for (int j = 0; j < 4; ++j) {
            if (!valid[j]) continue;
#pragma unroll
            for (int q = 0; q < 4; ++q) {
                float4 o = {acc[j][4 * q], acc[j][4 * q + 1], acc[j][4 * q + 2], acc[j][4 * q + 3]};
                out4[(n0 + j) * 16 + (h0 >> 2) + q] = o;
            }
        }
    } else {
        int hb = blockIdx.x - nbg;
        int i0 = (hb * 256 + threadIdx.x) * 4;
        if (i0 + 3 < e) {
            int4 c = *(const int4*)(col + i0);
            atomicAdd(&icnt[c.x], 1);
            atomicAdd(&icnt[c.y], 1);
            atomicAdd(&icnt[c.z], 1);
            atomicAdd(&icnt[c.w], 1);
        } else {
            for (int i = i0; i < e; ++i) atomicAdd(&icnt[col[i]], 1);
        }
    }
}

// ---------------------------------------------------------------------------
// exclusive scan of icnt[N] -> offs[N+1]; scan3 also writes dinv + zeros icnt
// ---------------------------------------------------------------------------
__global__ __launch_bounds__(256) void k_scan1(const int* __restrict__ icnt, int* part, int n) {
    __shared__ int sd[256];
    int base = blockIdx.x * SCAN_EPB;
    int s = 0;
#pragma unroll
    for (int j = 0; j < 4; ++j) {
        int idx = base + threadIdx.x * 4 + j;
        if (idx < n) s += icnt[idx];
    }
    sd[threadIdx.x] = s;
    __syncthreads();
    for (int off = 128; off > 0; off >>= 1) {
        if (threadIdx.x < off) sd[threadIdx.x] += sd[threadIdx.x + off];
        __syncthreads();
    }
    if (threadIdx.x == 0) part[blockIdx.x] = sd[0];
}

__global__ void k_scan2(int* part, int nb, int* offs, int n, int e) {
    if (threadIdx.x == 0) {
        int acc = 0;
        for (int i = 0; i < nb; ++i) { int v = part[i]; part[i] = acc; acc += v; }
        offs[n] = e;
    }
}

__global__ __launch_bounds__(256) void k_scan3(int* icnt, const int* __restrict__ part,
                                               int* offs, float* dinv, int n) {
    __shared__ int sd[256];
    int base = blockIdx.x * SCAN_EPB;
    int idx0 = base + threadIdx.x * 4;
    int v[4];
    int s = 0;
#pragma unroll
    for (int j = 0; j < 4; ++j) {
        int idx = idx0 + j;
        v[j] = (idx < n) ? icnt[idx] : 0;
        s += v[j];
    }
    sd[threadIdx.x] = s;
    __syncthreads();
    for (int off = 1; off < 256; off <<= 1) {
        int mine = sd[threadIdx.x];
        int add = (threadIdx.x >= off) ? sd[threadIdx.x - off] : 0;
        __syncthreads();
        sd[threadIdx.x] = mine + add;
        __syncthreads();
    }
    int run = part[blockIdx.x] + sd[threadIdx.x] - s;  // exclusive prefix
#pragma unroll
    for (int j = 0; j < 4; ++j) {
        int idx = idx0 + j;
        if (idx < n) {
            offs[idx] = run;
            icnt[idx] = 0;                              // reset as fill cursor
            dinv[idx] = rsqrtf((float)(v[j] + 1));      // +1 self-loop
        }
        run += v[j];
    }
}

// ---------------------------------------------------------------------------
// k_fill: scatter edge sources into CSR slots, 4 edges/thread for ILP
// ---------------------------------------------------------------------------
__global__ __launch_bounds__(256) void k_fill(const int* __restrict__ row, const int* __restrict__ col,
                                              const int* __restrict__ offs, int* icnt,
                                              int* csr_row, int e) {
    int i0 = (blockIdx.x * 256 + threadIdx.x) * 4;
    if (i0 + 3 < e) {
        int4 r = *(const int4*)(row + i0);
        int4 c = *(const int4*)(col + i0);
        int s0 = offs[c.x] + atomicAdd(&icnt[c.x], 1);
        int s1 = offs[c.y] + atomicAdd(&icnt[c.y], 1);
        int s2 = offs[c.z] + atomicAdd(&icnt[c.z], 1);
        int s3 = offs[c.w] + atomicAdd(&icnt[c.w], 1);
        csr_row[s0] = r.x;
        csr_row[s1] = r.y;
        csr_row[s2] = r.z;
        csr_row[s3] = r.w;
    } else {
        for (int i = i0; i < e; ++i) {
            int c = col[i];
            int slot = offs[c] + atomicAdd(&icnt[c], 1);
            csr_row[slot] = row[i];
        }
    }
}

// ---------------------------------------------------------------------------
// k_applygemm2: fused  bufB = relu(scale*(A_hat @ bufA) + shift) @ W2^T
// Phase A: 128 nodes/block gathered via CSR (16 lanes/node), act1, into LDS.
// Phase B: GEMM from LDS tile (row pad 17 float4 to spread banks).
// ---------------------------------------------------------------------------
#define APG_NODES 128
__global__ __launch_bounds__(256) void k_applygemm2(
    const float* __restrict__ h, const float* __restrict__ dinv,
    const int* __restrict__ offs, const int* __restrict__ csr_row,
    const float* __restrict__ W,
    const float* __restrict__ sc, const float* __restrict__ sh,
    float* __restrict__ out, int n) {
    __shared__ float4 Wl[1024];
    __shared__ float4 scl[16], shl[16];
    __shared__ float4 g[APG_NODES * 17];

    const float4* W4 = (const float4*)W;
    for (int i = threadIdx.x; i < 1024; i += 256) Wl[i] = W4[i];
    if (threadIdx.x < 16) {
        scl[threadIdx.x] = ((const float4*)sc)[threadIdx.x];
        shl[threadIdx.x] = ((const float4*)sh)[threadIdx.x];
    }
    __syncthreads();

    int node0 = blockIdx.x * APG_NODES;
    const float4* h4 = (const float4*)h;
    int q = threadIdx.x & 15;

    // ---- phase A: gather + act1 ----
    for (int it = 0; it < 8; ++it) {
        int il = it * 16 + (threadIdx.x >> 4);
        int i = node0 + il;
        if (i < n) {
            float di = dinv[i];
            float4 acc = h4[i * 16 + q];
            float dd = di * di;
            acc.x *= dd; acc.y *= dd; acc.z *= dd; acc.w *= dd;
            int k = offs[i], end = offs[i + 1];
            for (; k + 1 < end; k += 2) {
                int r0 = csr_row[k], r1 = csr_row[k + 1];
                float n0 = dinv[r0] * di, n1 = dinv[r1] * di;
                float4 v0 = h4[r0 * 16 + q];
                float4 v1 = h4[r1 * 16 + q];
                acc.x += v0.x * n0 + v1.x * n1;
                acc.y += v0.y * n0 + v1.y * n1;
                acc.z += v0.z * n0 + v1.z * n1;
                acc.w += v0.w * n0 + v1.w * n1;
            }
            if (k < end) {
                int r0 = csr_row[k];
                float n0 = dinv[r0] * di;
                float4 v0 = h4[r0 * 16 + q];
                acc.x += v0.x * n0;
                acc.y += v0.y * n0;
                acc.z += v0.z * n0;
                acc.w += v0.w * n0;
            }
            float4 s = scl[q], b = shl[q];
            acc.x = fmaxf(acc.x * s.x + b.x, 0.0f);
            acc.y = fmaxf(acc.y * s.y + b.y, 0.0f);
            acc.z = fmaxf(acc.z * s.z + b.z, 0.0f);
            acc.w = fmaxf(acc.w * s.w + b.w, 0.0f);
            g[il * 17 + q] = acc;
        }
    }
    __syncthreads();

    // ---- phase B: GEMM from LDS ----
    int hg = threadIdx.x >> 6;
    int h0 = hg * 16;
    int ng = threadIdx.x & 63;
    int loc[2] = {ng, ng + 64};
    float acc[2][16];
#pragma unroll
    for (int j = 0; j < 2; ++j)
#pragma unroll
        for (int k = 0; k < 16; ++k) acc[j][k] = 0.0f;

    for (int f4 = 0; f4 < 16; ++f4) {
        float4 xv0 = g[loc[0] * 17 + f4];
        float4 xv1 = g[loc[1] * 17 + f4];
#pragma unroll
        for (int hh = 0; hh < 16; ++hh) {
            float4 w = Wl[(h0 + hh) * 16 + f4];
            acc[0][hh] += xv0.x * w.x + xv0.y * w.y + xv0.z * w.z + xv0.w * w.w;
            acc[1][hh] += xv1.x * w.x + xv1.y * w.y + xv1.z * w.z + xv1.w * w.w;
        }
    }

    float4* out4 = (float4*)out;
#pragma unroll
    for (int j = 0; j < 2; ++j) {
        int i = node0 + loc[j];
        if (i < n) {
#pragma unroll
            for (int qq = 0; qq < 4; ++qq) {
                float4 o = {acc[j][4 * qq], acc[j][4 * qq + 1], acc[j][4 * qq + 2], acc[j][4 * qq + 3]};
                out4[i * 16 + (h0 >> 2) + qq] = o;
            }
        }
    }
}

// ---------------------------------------------------------------------------
// k_applypool: fused  gather(A_hat @ bufB) -> act2 -> per-graph LDS partial
// sums -> few global atomics. batch[] is sorted so a 128-node window spans a
// contiguous (usually 1-2) graph range.
// ---------------------------------------------------------------------------
#define APL_NODES 128
__global__ __launch_bounds__(256) void k_applypool(
    const float* __restrict__ h, const float* __restrict__ dinv,
    const int* __restrict__ offs, const int* __restrict__ csr_row,
    const int* __restrict__ batch,
    const float* __restrict__ sc, const float* __restrict__ sh,
    float* gsum, float* gcnt, int n) {
    __shared__ float spart[64 * 64];
    __shared__ float scnt[64];
    int node0 = blockIdx.x * APL_NODES;
    int last = min(node0 + APL_NODES - 1, n - 1);
    int g0 = batch[node0];
    int rc = batch[last] - g0 + 1;  // contiguous range, <= 64
    for (int idx = threadIdx.x; idx < rc * 64; idx += 256) spart[idx] = 0.0f;
    if (threadIdx.x < rc) scnt[threadIdx.x] = 0.0f;
    __syncthreads();

    const float4* h4 = (const float4*)h;
    int q = threadIdx.x & 15;
    float4 s4 = ((const float4*)sc)[q];
    float4 b4 = ((const float4*)sh)[q];

    for (int it = 0; it < APL_NODES / 16; ++it) {
        int i = node0 + it * 16 + (threadIdx.x >> 4);
        if (i < n) {
            float di = dinv[i];
            float4 acc = h4[i * 16 + q];
            float dd = di * di;
            acc.x *= dd; acc.y *= dd; acc.z *= dd; acc.w *= dd;
            int k = offs[i], end = offs[i + 1];
            for (; k + 1 < end; k += 2) {
                int r0 = csr_row[k], r1 = csr_row[k + 1];
                float n0 = dinv[r0] * di, n1 = dinv[r1] * di;
                float4 v0 = h4[r0 * 16 + q];
                float4 v1 = h4[r1 * 16 + q];
                acc.x += v0.x * n0 + v1.x * n1;
                acc.y += v0.y * n0 + v1.y * n1;
                acc.z += v0.z * n0 + v1.z * n1;
                acc.w += v0.w * n0 + v1.w * n1;
            }
            if (k < end) {
                int r0 = csr_row[k];
                float n0 = dinv[r0] * di;
                float4 v0 = h4[r0 * 16 + q];
                acc.x += v0.x * n0;
                acc.y += v0.y * n0;
                acc.z += v0.z * n0;
                acc.w += v0.w * n0;
            }
            acc.x = fmaxf(acc.x * s4.x + b4.x, 0.0f);
            acc.y = fmaxf(acc.y * s4.y + b4.y, 0.0f);
            acc.z = fmaxf(acc.z * s4.z + b4.z, 0.0f);
            acc.w = fmaxf(acc.w * s4.w + b4.w, 0.0f);
            int gl = batch[i] - g0;
            float* p = &spart[gl * 64 + q * 4];
            atomicAdd(p + 0, acc.x);
            atomicAdd(p + 1, acc.y);
            atomicAdd(p + 2, acc.z);
            atomicAdd(p + 3, acc.w);
            if (q == 0) atomicAdd(&scnt[gl], 1.0f);
        }
    }
    __syncthreads();
    for (int idx = threadIdx.x; idx < rc * 64; idx += 256) {
        int gl = idx >> 6, f = idx & 63;
        atomicAdd(&gsum[(g0 + gl) * 64 + f], spart[idx]);
    }
    if (threadIdx.x < rc) atomicAdd(&gcnt[g0 + threadIdx.x], scnt[threadIdx.x]);
}

// ---------------------------------------------------------------------------
// MLP head
// ---------------------------------------------------------------------------
__global__ void k_mlp(const float* __restrict__ gsum, const float* __restrict__ gcnt,
                      const float* __restrict__ l1W, const float* __restrict__ l1b,
                      const float* __restrict__ l2W, const float* __restrict__ l2b,
                      float* __restrict__ outp) {
    int g = threadIdx.x;
    if (g >= 64) return;
    float inv = 1.0f / fmaxf(gcnt[g], 1.0f);
    float p[64];
#pragma unroll
    for (int hh = 0; hh < 64; ++hh) p[hh] = gsum[g * 64 + hh] * inv;
    float o = l2b[0];
    for (int j = 0; j < 32; ++j) {
        float a = l1b[j];
#pragma unroll
        for (int hh = 0; hh < 64; ++hh) a += p[hh] * l1W[j * 64 + hh];
        o += fmaxf(a, 0.0f) * l2W[j];
    }
    outp[g] = o;
}

// ---------------------------------------------------------------------------
extern "C" void kernel_launch(void* const* d_in, const int* in_sizes, int n_in,
                              void* d_out, int out_size, void* d_ws, size_t ws_size,
                              hipStream_t stream) {
    const float* x    = (const float*)d_in[0];
    const int*  ei    = (const int*)d_in[1];
    const int*  batch = (const int*)d_in[2];
    const float* W1   = (const float*)d_in[3];
    const float* b1   = (const float*)d_in[4];
    const float* W2   = (const float*)d_in[5];
    const float* b2   = (const float*)d_in[6];
    const float* bn1g = (const float*)d_in[7];
    const float* bn1b = (const float*)d_in[8];
    const float* bn1m = (const float*)d_in[9];
    const float* bn1v = (const float*)d_in[10];
    const float* bn2g = (const float*)d_in[11];
    const float* bn2b = (const float*)d_in[12];
    const float* bn2m = (const float*)d_in[13];
    const float* bn2v = (const float*)d_in[14];
    const float* l1W  = (const float*)d_in[15];
    const float* l1b  = (const float*)d_in[16];
    const float* l2W  = (const float*)d_in[17];
    const float* l2b  = (const float*)d_in[18];
    float* out = (float*)d_out;

    const int N = in_sizes[0] / 64;  // 100000
    const int E = in_sizes[1] / 2;   // 1000000
    const int* row  = ei;
    const int* colp = ei + E;

    // workspace layout (all offsets multiple of 4 elems -> 16B aligned)
    int*   icnt = (int*)d_ws;                    // N
    int*   offs = icnt + N;                      // N+4
    float* dinv = (float*)(offs + N + 4);        // N
    float* sc1  = dinv + N;                      // 64
    float* sh1  = sc1 + 64;
    float* sc2  = sh1 + 64;
    float* sh2  = sc2 + 64;
    float* gsum = sh2 + 64;                      // 4096
    float* gcnt = gsum + 4096;                   // 64
    int*   csr_row = (int*)(gcnt + 64);          // E
    float* bufA = (float*)(csr_row + E);         // N*64
    float* bufB = bufA + (size_t)N * 64;         // N*64
    int* partials = (int*)(bufB + (size_t)N * 64);  // nb_scan ints (used only pre-bufB)

    int nb_n    = (N + 255) / 256;
    int nb_e4   = ((E + 3) / 4 + 255) / 256;
    int nb_scan = (N + SCAN_EPB - 1) / SCAN_EPB;
    int nb_apg  = (N + APG_NODES - 1) / APG_NODES;
    int nb_apl  = (N + APL_NODES - 1) / APL_NODES;

    // 1. zero + params
    k_pre<<<nb_n, 256, 0, stream>>>(icnt, gsum, gcnt, N,
                                    b1, bn1g, bn1b, bn1m, bn1v,
                                    b2, bn2g, bn2b, bn2m, bn2v,
                                    sc1, sh1, sc2, sh2);
    // 2. gemm1 + degree histogram (independent halves)
    k_histgemm<<<nb_n + nb_e4, 256, 0, stream>>>(nb_n, x, W1, bufA, N, colp, icnt, E);
    // 3-5. scan (+dinv)
    k_scan1<<<nb_scan, 256, 0, stream>>>(icnt, partials, N);
    k_scan2<<<1, 64, 0, stream>>>(partials, nb_scan, offs, N, E);
    k_scan3<<<nb_scan, 256, 0, stream>>>(icnt, partials, offs, dinv, N);
    // 6. CSR fill
    k_fill<<<nb_e4, 256, 0, stream>>>(row, colp, offs, icnt, csr_row, E);
    // 7. fused apply1 + act1 + gemm2
    k_applygemm2<<<nb_apg, 256, 0, stream>>>(bufA, dinv, offs, csr_row, W2, sc1, sh1, bufB, N);
    // 8. fused apply2 + act2 + pool
    k_applypool<<<nb_apl, 256, 0, stream>>>(bufB, dinv, offs, csr_row, batch, sc2, sh2, gsum, gcnt, N);
    // 9. head
    k_mlp<<<1, 64, 0, stream>>>(gsum, gcnt, l1W, l1b, l2W, l2b, out);
}

// Round 4
// 396.933 us; speedup vs baseline: 1.1904x; 1.1904x over previous
//
#include <hip/hip_runtime.h>
#include <math.h>

#define EPS_BN 1e-5f
#define SCAN_EPB 1024

// ---------------------------------------------------------------------------
// k_pre: zero icnt/gsum/gcnt, sentinel-fill csr_row (=n), zero sentinel rows
// of bufA/bufB, dinv[n]=0, fold conv-bias+BN into per-feature scale/shift.
// ---------------------------------------------------------------------------
__global__ __launch_bounds__(256) void k_pre(int* icnt, float* gsum, float* gcnt, int n,
    int* csr_row, int epad, float* dinv, float* rowA, float* rowB,
    const float* b1, const float* g1, const float* bb1, const float* m1, const float* v1,
    const float* b2, const float* g2, const float* bb2, const float* m2, const float* v2,
    float* sc1, float* sh1, float* sc2, float* sh2) {
    int i = blockIdx.x * 256 + threadIdx.x;
    if (i < n) icnt[i] = 0;
    if (i < epad) csr_row[i] = n;      // sentinel: contributes 0 (dinv[n]=0)
    if (i < 4096) gsum[i] = 0.0f;
    if (i < 64) { gcnt[i] = 0.0f; rowA[i] = 0.0f; rowB[i] = 0.0f; }
    if (i == 0) dinv[n] = 0.0f;
    if (blockIdx.x == 0 && threadIdx.x < 64) {
        int t = threadIdx.x;
        float s1 = g1[t] / sqrtf(v1[t] + EPS_BN);
        sc1[t] = s1;
        sh1[t] = (b1[t] - m1[t]) * s1 + bb1[t];
        float s2 = g2[t] / sqrtf(v2[t] + EPS_BN);
        sc2[t] = s2;
        sh2[t] = (b2[t] - m2[t]) * s2 + bb2[t];
    }
}

// ---------------------------------------------------------------------------
// k_hist: in-degree histogram, 4 edges/thread for ILP
// ---------------------------------------------------------------------------
__global__ __launch_bounds__(256) void k_hist(const int* __restrict__ col, int* icnt, int e) {
    int i0 = (blockIdx.x * 256 + threadIdx.x) * 4;
    if (i0 + 3 < e) {
        int c0 = col[i0], c1 = col[i0 + 1], c2 = col[i0 + 2], c3 = col[i0 + 3];
        atomicAdd(&icnt[c0], 1);
        atomicAdd(&icnt[c1], 1);
        atomicAdd(&icnt[c2], 1);
        atomicAdd(&icnt[c3], 1);
    } else {
        for (int i = i0; i < e; ++i) atomicAdd(&icnt[col[i]], 1);
    }
}

// ---------------------------------------------------------------------------
// exclusive scan of PADDED counts (ceil(deg/4)*4) -> offs[N+1]
// scan3 also writes dinv (from real deg) and zeros icnt (fill cursor).
// ---------------------------------------------------------------------------
__global__ __launch_bounds__(256) void k_scan1(const int* __restrict__ icnt, int* part, int n) {
    __shared__ int sd[256];
    int base = blockIdx.x * SCAN_EPB;
    int s = 0;
#pragma unroll
    for (int j = 0; j < 4; ++j) {
        int idx = base + threadIdx.x * 4 + j;
        if (idx < n) s += (icnt[idx] + 3) & ~3;
    }
    sd[threadIdx.x] = s;
    __syncthreads();
    for (int off = 128; off > 0; off >>= 1) {
        if (threadIdx.x < off) sd[threadIdx.x] += sd[threadIdx.x + off];
        __syncthreads();
    }
    if (threadIdx.x == 0) part[blockIdx.x] = sd[0];
}

__global__ void k_scan2(int* part, int nb, int* offs, int n) {
    if (threadIdx.x == 0) {
        int acc = 0;
        for (int i = 0; i < nb; ++i) { int v = part[i]; part[i] = acc; acc += v; }
        offs[n] = acc;  // total padded slot count
    }
}

__global__ __launch_bounds__(256) void k_scan3(int* icnt, const int* __restrict__ part,
                                               int* offs, float* dinv, int n) {
    __shared__ int sd[256];
    int base = blockIdx.x * SCAN_EPB;
    int idx0 = base + threadIdx.x * 4;
    int v[4], vp[4];
    int s = 0;
#pragma unroll
    for (int j = 0; j < 4; ++j) {
        int idx = idx0 + j;
        v[j] = (idx < n) ? icnt[idx] : 0;
        vp[j] = (v[j] + 3) & ~3;
        s += vp[j];
    }
    sd[threadIdx.x] = s;
    __syncthreads();
    for (int off = 1; off < 256; off <<= 1) {
        int mine = sd[threadIdx.x];
        int add = (threadIdx.x >= off) ? sd[threadIdx.x - off] : 0;
        __syncthreads();
        sd[threadIdx.x] = mine + add;
        __syncthreads();
    }
    int run = part[blockIdx.x] + sd[threadIdx.x] - s;  // exclusive padded prefix
#pragma unroll
    for (int j = 0; j < 4; ++j) {
        int idx = idx0 + j;
        if (idx < n) {
            offs[idx] = run;
            icnt[idx] = 0;                              // reset as fill cursor
            dinv[idx] = rsqrtf((float)(v[j] + 1));      // +1 self-loop
        }
        run += vp[j];
    }
}

// ---------------------------------------------------------------------------
// k_fillgemm: block-role split.
// Blocks [0,nbg): GEMM1 out = x @ W1^T (reads only x,W1 — independent of fill)
// Blocks [nbg,..): CSR fill, 4 edges/thread.
// ---------------------------------------------------------------------------
__global__ __launch_bounds__(256) void k_fillgemm(int nbg,
    const float* __restrict__ in, const float* __restrict__ W, float* __restrict__ out, int n,
    const int* __restrict__ row, const int* __restrict__ col,
    const int* __restrict__ offs, int* icnt, int* csr_row, int e) {
    __shared__ float4 Wl[1024];  // [h][f4]
    if ((int)blockIdx.x < nbg) {
        const float4* W4 = (const float4*)W;
        for (int i = threadIdx.x; i < 1024; i += 256) Wl[i] = W4[i];
        __syncthreads();
        int hg = threadIdx.x >> 6;
        int h0 = hg * 16;
        int ng = threadIdx.x & 63;
        int n0 = blockIdx.x * 256 + 4 * ng;
        float acc[4][16];
#pragma unroll
        for (int j = 0; j < 4; ++j)
#pragma unroll
            for (int k = 0; k < 16; ++k) acc[j][k] = 0.0f;
        const float4* in4 = (const float4*)in;
        bool valid[4];
#pragma unroll
        for (int j = 0; j < 4; ++j) valid[j] = (n0 + j) < n;
        for (int f4 = 0; f4 < 16; ++f4) {
            float4 xv[4];
#pragma unroll
            for (int j = 0; j < 4; ++j)
                xv[j] = valid[j] ? in4[(n0 + j) * 16 + f4] : float4{0.f, 0.f, 0.f, 0.f};
#pragma unroll
            for (int hh = 0; hh < 16; ++hh) {
                float4 w = Wl[(h0 + hh) * 16 + f4];
#pragma unroll
                for (int j = 0; j < 4; ++j) {
                    acc[j][hh] += xv[j].x * w.x;
                    acc[j][hh] += xv[j].y * w.y;
                    acc[j][hh] += xv[j].z * w.z;
                    acc[j][hh] += xv[j].w * w.w;
                }
            }
        }
        float4* out4 = (float4*)out;
#pragma unroll
        for (int j = 0; j < 4; ++j) {
            if (!valid[j]) continue;
#pragma unroll
            for (int q = 0; q < 4; ++q) {
                float4 o = {acc[j][4 * q], acc[j][4 * q + 1], acc[j][4 * q + 2], acc[j][4 * q + 3]};
                out4[(n0 + j) * 16 + (h0 >> 2) + q] = o;
            }
        }
    } else {
        int hb = blockIdx.x - nbg;
        int i0 = (hb * 256 + threadIdx.x) * 4;
        if (i0 + 3 < e) {
            int r0 = row[i0], r1 = row[i0 + 1], r2 = row[i0 + 2], r3 = row[i0 + 3];
            int c0 = col[i0], c1 = col[i0 + 1], c2 = col[i0 + 2], c3 = col[i0 + 3];
            int s0 = offs[c0] + atomicAdd(&icnt[c0], 1);
            int s1 = offs[c1] + atomicAdd(&icnt[c1], 1);
            int s2 = offs[c2] + atomicAdd(&icnt[c2], 1);
            int s3 = offs[c3] + atomicAdd(&icnt[c3], 1);
            csr_row[s0] = r0;
            csr_row[s1] = r1;
            csr_row[s2] = r2;
            csr_row[s3] = r3;
        } else {
            for (int i = i0; i < e; ++i) {
                int c = col[i];
                int slot = offs[c] + atomicAdd(&icnt[c], 1);
                csr_row[slot] = row[i];
            }
        }
    }
}

// ---------------------------------------------------------------------------
// k_apply: CSR pull with padded segments. 16 lanes/node, float4/lane.
// Inner loop: one aligned int4 index load + 4 INDEPENDENT row gathers.
// Pad entries point at sentinel row n with dinv[n]=0 -> contribute 0.
// ---------------------------------------------------------------------------
__global__ __launch_bounds__(256) void k_apply(const float* __restrict__ h, const float* __restrict__ dinv,
                                               const int* __restrict__ offs, const int* __restrict__ csr_row,
                                               float* __restrict__ out, int n) {
    int gid = blockIdx.x * 256 + threadIdx.x;
    int i = gid >> 4, q = gid & 15;
    if (i >= n) return;
    const float4* h4 = (const float4*)h;
    float di = dinv[i];
    float4 acc = h4[i * 16 + q];
    float dd = di * di;
    acc.x *= dd; acc.y *= dd; acc.z *= dd; acc.w *= dd;

    int k = offs[i], kend = offs[i + 1];
    for (; k < kend; k += 4) {
        int4 rr = *(const int4*)(csr_row + k);  // aligned: k multiple of 4
        float w0 = dinv[rr.x] * di;
        float w1 = dinv[rr.y] * di;
        float w2 = dinv[rr.z] * di;
        float w3 = dinv[rr.w] * di;
        float4 v0 = h4[rr.x * 16 + q];
        float4 v1 = h4[rr.y * 16 + q];
        float4 v2 = h4[rr.z * 16 + q];
        float4 v3 = h4[rr.w * 16 + q];
        acc.x += v0.x * w0 + v1.x * w1 + v2.x * w2 + v3.x * w3;
        acc.y += v0.y * w0 + v1.y * w1 + v2.y * w2 + v3.y * w3;
        acc.z += v0.z * w0 + v1.z * w1 + v2.z * w2 + v3.z * w3;
        acc.w += v0.w * w0 + v1.w * w1 + v2.w * w2 + v3.w * w3;
    }
    ((float4*)out)[i * 16 + q] = acc;
}

// ---------------------------------------------------------------------------
// k_gemm2: out[n][64] = relu(in*sc+sh) @ W^T   (act1 folded into input read)
// ---------------------------------------------------------------------------
__global__ __launch_bounds__(256) void k_gemm2(const float* __restrict__ in, const float* __restrict__ W,
                                               const float* __restrict__ scale, const float* __restrict__ shift,
                                               float* __restrict__ out, int n) {
    __shared__ float4 Wl[1024];
    __shared__ float4 scl[16], shl[16];
    const float4* W4 = (const float4*)W;
    for (int i = threadIdx.x; i < 1024; i += 256) Wl[i] = W4[i];
    if (threadIdx.x < 16) {
        scl[threadIdx.x] = ((const float4*)scale)[threadIdx.x];
        shl[threadIdx.x] = ((const float4*)shift)[threadIdx.x];
    }
    __syncthreads();

    int hg = threadIdx.x >> 6;
    int h0 = hg * 16;
    int ng = threadIdx.x & 63;
    int n0 = blockIdx.x * 256 + 4 * ng;

    float acc[4][16];
#pragma unroll
    for (int j = 0; j < 4; ++j)
#pragma unroll
        for (int k = 0; k < 16; ++k) acc[j][k] = 0.0f;

    const float4* in4 = (const float4*)in;
    bool valid[4];
#pragma unroll
    for (int j = 0; j < 4; ++j) valid[j] = (n0 + j) < n;

    for (int f4 = 0; f4 < 16; ++f4) {
        float4 sc = scl[f4], sh = shl[f4];
        float4 xv[4];
#pragma unroll
        for (int j = 0; j < 4; ++j) {
            float4 v = valid[j] ? in4[(n0 + j) * 16 + f4] : float4{0.f, 0.f, 0.f, 0.f};
            v.x = fmaxf(v.x * sc.x + sh.x, 0.0f);
            v.y = fmaxf(v.y * sc.y + sh.y, 0.0f);
            v.z = fmaxf(v.z * sc.z + sh.z, 0.0f);
            v.w = fmaxf(v.w * sc.w + sh.w, 0.0f);
            xv[j] = v;
        }
#pragma unroll
        for (int hh = 0; hh < 16; ++hh) {
            float4 w = Wl[(h0 + hh) * 16 + f4];
#pragma unroll
            for (int j = 0; j < 4; ++j) {
                acc[j][hh] += xv[j].x * w.x;
                acc[j][hh] += xv[j].y * w.y;
                acc[j][hh] += xv[j].z * w.z;
                acc[j][hh] += xv[j].w * w.w;
            }
        }
    }

    float4* out4 = (float4*)out;
#pragma unroll
    for (int j = 0; j < 4; ++j) {
        if (!valid[j]) continue;
#pragma unroll
        for (int q = 0; q < 4; ++q) {
            float4 o = {acc[j][4 * q], acc[j][4 * q + 1], acc[j][4 * q + 2], acc[j][4 * q + 3]};
            out4[(n0 + j) * 16 + (h0 >> 2) + q] = o;
        }
    }
}

// ---------------------------------------------------------------------------
// k_applypool: gather(A_hat @ h) -> act2 -> per-graph LDS partials -> atomics.
// Padded int4 gather. batch[] sorted, 128-node window spans small graph range.
// ---------------------------------------------------------------------------
#define APL_NODES 128
__global__ __launch_bounds__(256) void k_applypool(
    const float* __restrict__ h, const float* __restrict__ dinv,
    const int* __restrict__ offs, const int* __restrict__ csr_row,
    const int* __restrict__ batch,
    const float* __restrict__ sc, const float* __restrict__ sh,
    float* gsum, float* gcnt, int n) {
    __shared__ float spart[64 * 64];
    __shared__ float scnt[64];
    int node0 = blockIdx.x * APL_NODES;
    int last = min(node0 + APL_NODES - 1, n - 1);
    int g0 = batch[node0];
    int rc = batch[last] - g0 + 1;  // contiguous, <= 64
    for (int idx = threadIdx.x; idx < rc * 64; idx += 256) spart[idx] = 0.0f;
    if (threadIdx.x < rc) scnt[threadIdx.x] = 0.0f;
    __syncthreads();

    const float4* h4 = (const float4*)h;
    int q = threadIdx.x & 15;
    float4 s4 = ((const float4*)sc)[q];
    float4 b4 = ((const float4*)sh)[q];

    for (int it = 0; it < APL_NODES / 16; ++it) {
        int i = node0 + it * 16 + (threadIdx.x >> 4);
        if (i < n) {
            float di = dinv[i];
            float4 acc = h4[i * 16 + q];
            float dd = di * di;
            acc.x *= dd; acc.y *= dd; acc.z *= dd; acc.w *= dd;
            int k = offs[i], kend = offs[i + 1];
            for (; k < kend; k += 4) {
                int4 rr = *(const int4*)(csr_row + k);
                float w0 = dinv[rr.x] * di;
                float w1 = dinv[rr.y] * di;
                float w2 = dinv[rr.z] * di;
                float w3 = dinv[rr.w] * di;
                float4 v0 = h4[rr.x * 16 + q];
                float4 v1 = h4[rr.y * 16 + q];
                float4 v2 = h4[rr.z * 16 + q];
                float4 v3 = h4[rr.w * 16 + q];
                acc.x += v0.x * w0 + v1.x * w1 + v2.x * w2 + v3.x * w3;
                acc.y += v0.y * w0 + v1.y * w1 + v2.y * w2 + v3.y * w3;
                acc.z += v0.z * w0 + v1.z * w1 + v2.z * w2 + v3.z * w3;
                acc.w += v0.w * w0 + v1.w * w1 + v2.w * w2 + v3.w * w3;
            }
            acc.x = fmaxf(acc.x * s4.x + b4.x, 0.0f);
            acc.y = fmaxf(acc.y * s4.y + b4.y, 0.0f);
            acc.z = fmaxf(acc.z * s4.z + b4.z, 0.0f);
            acc.w = fmaxf(acc.w * s4.w + b4.w, 0.0f);
            int gl = batch[i] - g0;
            float* p = &spart[gl * 64 + q * 4];
            atomicAdd(p + 0, acc.x);
            atomicAdd(p + 1, acc.y);
            atomicAdd(p + 2, acc.z);
            atomicAdd(p + 3, acc.w);
            if (q == 0) atomicAdd(&scnt[gl], 1.0f);
        }
    }
    __syncthreads();
    for (int idx = threadIdx.x; idx < rc * 64; idx += 256) {
        int gl = idx >> 6, f = idx & 63;
        atomicAdd(&gsum[(g0 + gl) * 64 + f], spart[idx]);
    }
    if (threadIdx.x < rc) atomicAdd(&gcnt[g0 + threadIdx.x], scnt[threadIdx.x]);
}

// ---------------------------------------------------------------------------
// MLP head
// ---------------------------------------------------------------------------
__global__ void k_mlp(const float* __restrict__ gsum, const float* __restrict__ gcnt,
                      const float* __restrict__ l1W, const float* __restrict__ l1b,
                      const float* __restrict__ l2W, const float* __restrict__ l2b,
                      float* __restrict__ outp) {
    int g = threadIdx.x;
    if (g >= 64) return;
    float inv = 1.0f / fmaxf(gcnt[g], 1.0f);
    float p[64];
#pragma unroll
    for (int hh = 0; hh < 64; ++hh) p[hh] = gsum[g * 64 + hh] * inv;
    float o = l2b[0];
    for (int j = 0; j < 32; ++j) {
        float a = l1b[j];
#pragma unroll
        for (int hh = 0; hh < 64; ++hh) a += p[hh] * l1W[j * 64 + hh];
        o += fmaxf(a, 0.0f) * l2W[j];
    }
    outp[g] = o;
}

// ---------------------------------------------------------------------------
extern "C" void kernel_launch(void* const* d_in, const int* in_sizes, int n_in,
                              void* d_out, int out_size, void* d_ws, size_t ws_size,
                              hipStream_t stream) {
    const float* x    = (const float*)d_in[0];
    const int*  ei    = (const int*)d_in[1];
    const int*  batch = (const int*)d_in[2];
    const float* W1   = (const float*)d_in[3];
    const float* b1   = (const float*)d_in[4];
    const float* W2   = (const float*)d_in[5];
    const float* b2   = (const float*)d_in[6];
    const float* bn1g = (const float*)d_in[7];
    const float* bn1b = (const float*)d_in[8];
    const float* bn1m = (const float*)d_in[9];
    const float* bn1v = (const float*)d_in[10];
    const float* bn2g = (const float*)d_in[11];
    const float* bn2b = (const float*)d_in[12];
    const float* bn2m = (const float*)d_in[13];
    const float* bn2v = (const float*)d_in[14];
    const float* l1W  = (const float*)d_in[15];
    const float* l1b  = (const float*)d_in[16];
    const float* l2W  = (const float*)d_in[17];
    const float* l2b  = (const float*)d_in[18];
    float* out = (float*)d_out;

    const int N = in_sizes[0] / 64;  // 100000
    const int E = in_sizes[1] / 2;   // 1000000
    const int* row  = ei;
    const int* colp = ei + E;
    const int EPAD = ((E + 3 * N) + 19) & ~3;  // padded CSR capacity (mult of 4)

    // workspace layout (element offsets multiples of 4 -> 16B aligned)
    int*   icnt = (int*)d_ws;                    // N
    int*   offs = icnt + N;                      // N+4
    float* dinv = (float*)(offs + N + 4);        // N+4 (incl sentinel)
    float* sc1  = dinv + N + 4;                  // 64
    float* sh1  = sc1 + 64;
    float* sc2  = sh1 + 64;
    float* sh2  = sc2 + 64;
    float* gsum = sh2 + 64;                      // 4096
    float* gcnt = gsum + 4096;                   // 64
    int*   csr_row = (int*)(gcnt + 64);          // EPAD
    float* bufA = (float*)(csr_row + EPAD);      // (N+1)*64
    float* bufB = bufA + (size_t)(N + 1) * 64;   // (N+1)*64
    int*   partials = (int*)(bufB + (size_t)(N + 1) * 64);  // nb_scan

    int nb_n    = (N + 255) / 256;
    int nb_pre  = (EPAD > N ? EPAD + 255 : N + 255) / 256;
    int nb_e4   = ((E + 3) / 4 + 255) / 256;
    int nb_scan = (N + SCAN_EPB - 1) / SCAN_EPB;
    int nb_n16  = (N * 16 + 255) / 256;
    int nb_apl  = (N + APL_NODES - 1) / APL_NODES;

    // 1. zero/sentinel init + params
    k_pre<<<nb_pre, 256, 0, stream>>>(icnt, gsum, gcnt, N, csr_row, EPAD, dinv,
                                      bufA + (size_t)N * 64, bufB + (size_t)N * 64,
                                      b1, bn1g, bn1b, bn1m, bn1v,
                                      b2, bn2g, bn2b, bn2m, bn2v,
                                      sc1, sh1, sc2, sh2);
    // 2. degree histogram
    k_hist<<<nb_e4, 256, 0, stream>>>(colp, icnt, E);
    // 3-5. padded exclusive scan (+dinv)
    k_scan1<<<nb_scan, 256, 0, stream>>>(icnt, partials, N);
    k_scan2<<<1, 64, 0, stream>>>(partials, nb_scan, offs, N);
    k_scan3<<<nb_scan, 256, 0, stream>>>(icnt, partials, offs, dinv, N);
    // 6. gemm1 + CSR fill (independent halves, co-scheduled)
    k_fillgemm<<<nb_n + nb_e4, 256, 0, stream>>>(nb_n, x, W1, bufA, N,
                                                 row, colp, offs, icnt, csr_row, E);
    // 7. apply1: bufA -> bufB
    k_apply<<<nb_n16, 256, 0, stream>>>(bufA, dinv, offs, csr_row, bufB, N);
    // 8. gemm2 (act1 on read): bufB -> bufA
    k_gemm2<<<nb_n, 256, 0, stream>>>(bufB, W2, sc1, sh1, bufA, N);
    // 9. apply2 + act2 + pool
    k_applypool<<<nb_apl, 256, 0, stream>>>(bufA, dinv, offs, csr_row, batch, sc2, sh2, gsum, gcnt, N);
    // 10. head
    k_mlp<<<1, 64, 0, stream>>>(gsum, gcnt, l1W, l1b, l2W, l2b, out);
}